// Round 9
// baseline (107.888 us; speedup 1.0000x reference)
//
#include <hip/hip_runtime.h>

// VectorQuantizer: B=32,D=64,H=64,W=64 -> N=131072 px; K=512 codes.
// out[0] = 1.25*mean((E[idx]-z)^2); out[1..] = Zq as [B,D,H,W].
// R8: SPLIT into homogeneous streaming kernels (R6's single kernel spent ~3x
// its pipe-floor on per-wave phase-chain latency; also fixes R5/R6's arena
// overflow where zqT[2110] ran past the 4608-B union slot).
//   prep: E -> fragment-major bf16 E16s + en2s (=|e|^2+2).
//   A (vq_argmin): wave=32px; stage Z*-2 -> LDS -> A-frags; depth-4 B ring
//      over all 512 codes; dist = en2 + (-2z).e via MFMA C-operand, in (1,3)
//      => raw uint bits order-monotone, low 9 bits = idx; merge across 16
//      column-lanes; write idx (coalesced i32) + loss cell. No store tail.
//   B (vq_scatter): block=64px; gather E[idx] rows (float4 x 64 rows/wave),
//      LDS transpose [64][65], store px-contiguous 256-B segs, nontemporal.
//   loss: reduce 4096 cells.

typedef __bf16 bf16x8 __attribute__((ext_vector_type(8)));
typedef float  f32x4  __attribute__((ext_vector_type(4)));
typedef int    i32x4  __attribute__((ext_vector_type(4)));

#define LOSS_SCALE (1.25f / 8388608.f)   // 1.25 / (N*D)

// ---- prep: E fp32 -> E16s (fragment-major bf16) + en2s ---------------------
// E16s (bf16 units): [((ct*2 + half)*64 + lane) * 8 + j]
//   lane=(q=lane>>4, m=lane&15): code c = ct*16+m, dim = half*32 + q*8 + j
__global__ __launch_bounds__(256) void vq_prep(const float* __restrict__ E,
                                               __bf16* __restrict__ E16s,
                                               float* __restrict__ en2s) {
  int tau = blockIdx.x * 256 + threadIdx.x;        // 4096 threads
  int lane = tau & 63, half = (tau >> 6) & 1, ct = tau >> 7;
  int m = lane & 15, q = lane >> 4;
  int c = ct * 16 + m;
  const float* src = E + c * 64 + half * 32 + q * 8;
  float4 s0 = *(const float4*)src;
  float4 s1 = *(const float4*)(src + 4);
  bf16x8 b;
  b[0] = (__bf16)s0.x; b[1] = (__bf16)s0.y; b[2] = (__bf16)s0.z; b[3] = (__bf16)s0.w;
  b[4] = (__bf16)s1.x; b[5] = (__bf16)s1.y; b[6] = (__bf16)s1.z; b[7] = (__bf16)s1.w;
  *(bf16x8*)(E16s + tau * 8) = b;
  if (half == 0) {
    const float4* row = (const float4*)(E + c * 64);
    float ss = 0.f;
    #pragma unroll
    for (int i = 0; i < 16; ++i) {
      float4 v = row[i];
      ss += v.x * v.x + v.y * v.y + v.z * v.z + v.w * v.w;
    }
    en2s[ct * 64 + lane] = ss + 2.0f;
  }
}

#define ARGMIN(KK, RV) { unsigned key_ = (__float_as_uint(RV) & 0xFFFFFE00u) | cvec; \
                         if (key_ < KK) KK = key_; }
#define MERGE16(KK) { unsigned o_; \
    o_ = __shfl_xor(KK, 1); if (o_ < KK) KK = o_; \
    o_ = __shfl_xor(KK, 2); if (o_ < KK) KK = o_; \
    o_ = __shfl_xor(KK, 4); if (o_ < KK) KK = o_; \
    o_ = __shfl_xor(KK, 8); if (o_ < KK) KK = o_; }

// ---- kernel A: argmin + loss cells + idx ----------------------------------
__global__ __launch_bounds__(256, 4) void vq_argmin(const float* __restrict__ in,
                                                    const __bf16* __restrict__ E16s,
                                                    const float* __restrict__ en2s,
                                                    int* __restrict__ idx_out,
                                                    float* __restrict__ cells) {
  __shared__ __bf16 Zl[4][2304];          // per-wave: 32 px x 72 (-2z, bf16)
  __shared__ int    idxl[4][32];

  const int t = threadIdx.x, lane = t & 63, w = t >> 6;
  const int q = lane >> 4, m = lane & 15;
  const int g = blockIdx.x * 4 + w;                 // wave tile 0..4095 (32 px)
  const int base = (g >> 7) * 262144 + ((g & 127) << 5);

  // ---- stage: lane loads 16 float2 (px 2m,2m+1) at d = q*16+j --------------
  float zn = 0.f;
  {
    float2 L[16];
    const float* p = in + base + (q * 16) * 4096 + 2 * m;
    #pragma unroll
    for (int j = 0; j < 16; ++j) L[j] = *(const float2*)(p + j * 4096);
    bf16x8 c00, c01, c10, c11;
    #pragma unroll
    for (int j = 0; j < 8; ++j) {
      c00[j] = (__bf16)(-2.f * L[j].x);
      c10[j] = (__bf16)(-2.f * L[j].y);
      c01[j] = (__bf16)(-2.f * L[j + 8].x);
      c11[j] = (__bf16)(-2.f * L[j + 8].y);
    }
    #pragma unroll
    for (int j = 0; j < 16; ++j) zn += L[j].x * L[j].x + L[j].y * L[j].y;
    __bf16* r0 = &Zl[w][(2 * m) * 72 + q * 16];
    __bf16* r1 = &Zl[w][(2 * m + 1) * 72 + q * 16];
    *(bf16x8*)r0 = c00; *(bf16x8*)(r0 + 8) = c01;
    *(bf16x8*)r1 = c10; *(bf16x8*)(r1 + 8) = c11;
  }
  __threadfence_block();                  // wave-local LDS visibility

  bf16x8 A00 = *(const bf16x8*)&Zl[w][(m) * 72 + q * 8];
  bf16x8 A01 = *(const bf16x8*)&Zl[w][(m) * 72 + 32 + q * 8];
  bf16x8 A10 = *(const bf16x8*)&Zl[w][(16 + m) * 72 + q * 8];
  bf16x8 A11 = *(const bf16x8*)&Zl[w][(16 + m) * 72 + 32 + q * 8];

  unsigned k00 = ~0u, k01 = ~0u, k02 = ~0u, k03 = ~0u;
  unsigned k10 = ~0u, k11 = ~0u, k12 = ~0u, k13 = ~0u;

  // ---- stream all 512 codes: 32 tiles, depth-4 prefetch ring ---------------
  const __bf16* Eb = E16s + lane * 8;     // + ct*1024 (+512 for B1)
  bf16x8 P0[4], P1[4];
  float  PE[4];
  #pragma unroll
  for (int i = 0; i < 4; ++i) {
    P0[i] = *(const bf16x8*)(Eb + i * 1024);
    P1[i] = *(const bf16x8*)(Eb + i * 1024 + 512);
    PE[i] = en2s[i * 64 + lane];
  }
  #pragma unroll
  for (int ct = 0; ct < 32; ++ct) {
    const int s = ct & 3;
    bf16x8 B0 = P0[s], B1 = P1[s];
    float  en = PE[s];
    {
      int nt = ct + 4; nt = nt > 31 ? 31 : nt;
      P0[s] = *(const bf16x8*)(Eb + nt * 1024);
      P1[s] = *(const bf16x8*)(Eb + nt * 1024 + 512);
      PE[s] = en2s[nt * 64 + lane];
    }
    f32x4 einit = {en, en, en, en};
    const unsigned cvec = (unsigned)(ct * 16 + m);
    f32x4 a0 = __builtin_amdgcn_mfma_f32_16x16x32_bf16(A00, B0, einit, 0, 0, 0);
    a0 = __builtin_amdgcn_mfma_f32_16x16x32_bf16(A01, B1, a0, 0, 0, 0);
    f32x4 a1 = __builtin_amdgcn_mfma_f32_16x16x32_bf16(A10, B0, einit, 0, 0, 0);
    a1 = __builtin_amdgcn_mfma_f32_16x16x32_bf16(A11, B1, a1, 0, 0, 0);
    ARGMIN(k00, a0[0]) ARGMIN(k01, a0[1]) ARGMIN(k02, a0[2]) ARGMIN(k03, a0[3])
    ARGMIN(k10, a1[0]) ARGMIN(k11, a1[1]) ARGMIN(k12, a1[2]) ARGMIN(k13, a1[3])
  }

  MERGE16(k00) MERGE16(k01) MERGE16(k02) MERGE16(k03)
  MERGE16(k10) MERGE16(k11) MERGE16(k12) MERGE16(k13)

  if (m == 0) {                           // publish winners: px = pt*16+q*4+r
    i32x4 w0, w1;
    w0[0] = (int)(k00 & 511u); w0[1] = (int)(k01 & 511u);
    w0[2] = (int)(k02 & 511u); w0[3] = (int)(k03 & 511u);
    w1[0] = (int)(k10 & 511u); w1[1] = (int)(k11 & 511u);
    w1[2] = (int)(k12 & 511u); w1[3] = (int)(k13 & 511u);
    *(i32x4*)&idxl[w][q * 4]      = w0;
    *(i32x4*)&idxl[w][16 + q * 4] = w1;
  }

  // ---- loss partial --------------------------------------------------------
  float ll = zn;
  if (m == 0) {
    ll += (__uint_as_float(k00) - 2.f) + (__uint_as_float(k01) - 2.f)
        + (__uint_as_float(k02) - 2.f) + (__uint_as_float(k03) - 2.f)
        + (__uint_as_float(k10) - 2.f) + (__uint_as_float(k11) - 2.f)
        + (__uint_as_float(k12) - 2.f) + (__uint_as_float(k13) - 2.f);
  }
  #pragma unroll
  for (int off = 1; off < 64; off <<= 1) ll += __shfl_xor(ll, off);
  if (lane == 0) cells[g] = ll;

  __threadfence_block();

  // ---- write idx: 32 contiguous i32 per wave (one 128-B segment) -----------
  if (lane < 32) idx_out[g * 32 + lane] = idxl[w][lane];
}

// ---- kernel B: gather E[idx] -> transpose -> coalesced Zq stores -----------
__global__ __launch_bounds__(256) void vq_scatter(const float* __restrict__ E,
                                                  const int* __restrict__ idx,
                                                  float* __restrict__ out) {
  __shared__ float zqT[64 * 65];          // [d][px], pad 65 (2-way banks, free)
  const int t = threadIdx.x;
  const int blk = blockIdx.x;             // 2048 blocks x 64 px
  const int px0 = blk * 64;
  const int r = t & 63, g4 = t >> 6;      // wave g4 handles dim group g4*16

  int row = idx[px0 + r];
  const float4* Er = (const float4*)(E + row * 64 + g4 * 16);
  #pragma unroll
  for (int u = 0; u < 4; ++u) {
    float4 v = Er[u];
    int d = g4 * 16 + u * 4;
    zqT[(d + 0) * 65 + r] = v.x;
    zqT[(d + 1) * 65 + r] = v.y;
    zqT[(d + 2) * 65 + r] = v.z;
    zqT[(d + 3) * 65 + r] = v.w;
  }
  __syncthreads();

  const int base = (blk >> 6) * 262144 + ((blk & 63) << 6);
  float* op = out + 1 + base + r;
  #pragma unroll
  for (int j = 0; j < 16; ++j) {
    int d = g4 + 4 * j;                   // wave-contiguous px => 256-B segments
    __builtin_nontemporal_store(zqT[d * 65 + r], op + d * 4096);
  }
}

// ---- tiny reduce: sum 4096 wave partials -> out[0] -------------------------
__global__ __launch_bounds__(256) void vq_loss(const float* __restrict__ cells,
                                               float* __restrict__ out) {
  __shared__ float wsum[4];
  int t = threadIdx.x;
  const float4* c4 = (const float4*)cells;         // 1024 float4
  float s = 0.f;
  #pragma unroll
  for (int j = 0; j < 4; ++j) {
    float4 v = c4[t + 256 * j];
    s += v.x + v.y + v.z + v.w;
  }
  #pragma unroll
  for (int off = 1; off < 64; off <<= 1) s += __shfl_xor(s, off);
  if ((t & 63) == 0) wsum[t >> 6] = s;
  __syncthreads();
  if (t == 0) out[0] = (wsum[0] + wsum[1] + wsum[2] + wsum[3]) * LOSS_SCALE;
}

extern "C" void kernel_launch(void* const* d_in, const int* in_sizes, int n_in,
                              void* d_out, int out_size, void* d_ws, size_t ws_size,
                              hipStream_t stream) {
  (void)in_sizes; (void)n_in; (void)out_size; (void)ws_size;
  const float* in = (const float*)d_in[0];   // [32,64,64,64]
  const float* E  = (const float*)d_in[1];   // [512,64]
  float* out = (float*)d_out;                // [1 + 8388608]
  __bf16* E16s  = (__bf16*)d_ws;                       // 64 KiB
  float*  en2s  = (float*)((char*)d_ws + 65536);       // 8 KiB
  float*  cells = (float*)((char*)d_ws + 73728);       // 16 KiB
  int*    idxb  = (int*)((char*)d_ws + 98304);         // 512 KiB

  vq_prep<<<16, 256, 0, stream>>>(E, E16s, en2s);
  vq_argmin<<<1024, 256, 0, stream>>>(in, E16s, en2s, idxb, cells);
  vq_scatter<<<2048, 256, 0, stream>>>(E, idxb, out);
  vq_loss<<<1, 256, 0, stream>>>(cells, out);
}

// Round 10
// 106.889 us; speedup vs baseline: 1.0094x; 1.0094x over previous
//
#include <hip/hip_runtime.h>

// VectorQuantizer: B=32,D=64,H=64,W=64 -> N=131072 px; K=512 codes.
// out[0] = 1.25*mean((E[idx]-z)^2); out[1..] = Zq as [B,D,H,W].
// R9 = R6 (best measured: barrier-free wave-per-32px; fragment-major E16s so
// B loads are 16B/lane fully coalesced; depth-4 B-prefetch ring; cooperative
// gather + LDS transpose; f32x2u stores) with:
//  - arena sized correctly (8448 B/wave flat; R6's union was under-sized and
//    zqT overflowed into the neighbor wave's slot),
//  - ring refill via (ct+4)&31 (no clamp-select; wrapped tiles are L1-hot),
//  - nontemporal loads of `in` / stores of `out` (read/written exactly once)
//    to keep L1 for the E16s/E streams.
// dist = en2 + (-2z).e via MFMA C operand, in (1,3) => raw uint bits are
// order-monotone; low 9 bits carry code idx. Loss -> cells -> tiny reducer.

typedef __bf16 bf16x8 __attribute__((ext_vector_type(8)));
typedef float  f32x4  __attribute__((ext_vector_type(4)));
typedef int    i32x4  __attribute__((ext_vector_type(4)));
typedef float  f32x2u __attribute__((ext_vector_type(2), aligned(4)));

#define LOSS_SCALE (1.25f / 8388608.f)   // 1.25 / (N*D)

// ---- prep: E fp32 -> E16s (fragment-major bf16) + en2s ---------------------
// E16s (bf16 units): [((ct*2 + half)*64 + lane) * 8 + j]
//   lane=(q=lane>>4, m=lane&15): code c = ct*16+m, dim = half*32 + q*8 + j
__global__ __launch_bounds__(256) void vq_prep(const float* __restrict__ E,
                                               __bf16* __restrict__ E16s,
                                               float* __restrict__ en2s) {
  int tau = blockIdx.x * 256 + threadIdx.x;        // 4096 threads
  int lane = tau & 63, half = (tau >> 6) & 1, ct = tau >> 7;
  int m = lane & 15, q = lane >> 4;
  int c = ct * 16 + m;
  const float* src = E + c * 64 + half * 32 + q * 8;
  float4 s0 = *(const float4*)src;
  float4 s1 = *(const float4*)(src + 4);
  bf16x8 b;
  b[0] = (__bf16)s0.x; b[1] = (__bf16)s0.y; b[2] = (__bf16)s0.z; b[3] = (__bf16)s0.w;
  b[4] = (__bf16)s1.x; b[5] = (__bf16)s1.y; b[6] = (__bf16)s1.z; b[7] = (__bf16)s1.w;
  *(bf16x8*)(E16s + tau * 8) = b;
  if (half == 0) {
    const float4* row = (const float4*)(E + c * 64);
    float ss = 0.f;
    #pragma unroll
    for (int i = 0; i < 16; ++i) {
      float4 v = row[i];
      ss += v.x * v.x + v.y * v.y + v.z * v.z + v.w * v.w;
    }
    en2s[ct * 64 + lane] = ss + 2.0f;
  }
}

#define ARGMIN(KK, RV) { unsigned key_ = (__float_as_uint(RV) & 0xFFFFFE00u) | cvec; \
                         if (key_ < KK) KK = key_; }
#define MERGE16(KK) { unsigned o_; \
    o_ = __shfl_xor(KK, 1); if (o_ < KK) KK = o_; \
    o_ = __shfl_xor(KK, 2); if (o_ < KK) KK = o_; \
    o_ = __shfl_xor(KK, 4); if (o_ < KK) KK = o_; \
    o_ = __shfl_xor(KK, 8); if (o_ < KK) KK = o_; }

__global__ __launch_bounds__(256, 4) void vq_main(const float* __restrict__ in,
                                                  const float* __restrict__ E,
                                                  const __bf16* __restrict__ E16s,
                                                  const float* __restrict__ en2s,
                                                  float* __restrict__ out,
                                                  float* __restrict__ cells) {
  // per-wave arena, 2112 floats = 8448 B: phase 1 = bf16 staging (needs 4608 B
  // as 32px x 72 bf16); phase 2 = fp32 zqT[64][33] (needs all 8448 B).
  __shared__ __align__(16) float arena[4][2112];
  __shared__ int idxl[4][32];

  const int t = threadIdx.x, lane = t & 63, w = t >> 6;
  const int q = lane >> 4, m = lane & 15;
  const int g = blockIdx.x * 4 + w;                 // wave tile 0..4095 (32 px)
  const int base = (g >> 7) * 262144 + ((g & 127) << 5);

  // ---- stage: lane loads 16 float2 (px 2m,2m+1) at d = q*16+j (nontemporal)
  __bf16* Zl = (__bf16*)&arena[w][0];
  float zn = 0.f;
  {
    float2 L[16];
    const float* p = in + base + (q * 16) * 4096 + 2 * m;
    #pragma unroll
    for (int j = 0; j < 16; ++j) {
      L[j].x = __builtin_nontemporal_load(p + j * 4096);
      L[j].y = __builtin_nontemporal_load(p + j * 4096 + 1);
    }
    bf16x8 c00, c01, c10, c11;
    #pragma unroll
    for (int j = 0; j < 8; ++j) {
      c00[j] = (__bf16)(-2.f * L[j].x);
      c10[j] = (__bf16)(-2.f * L[j].y);
      c01[j] = (__bf16)(-2.f * L[j + 8].x);
      c11[j] = (__bf16)(-2.f * L[j + 8].y);
    }
    #pragma unroll
    for (int j = 0; j < 16; ++j) zn += L[j].x * L[j].x + L[j].y * L[j].y;
    __bf16* r0 = &Zl[(2 * m) * 72 + q * 16];
    __bf16* r1 = &Zl[(2 * m + 1) * 72 + q * 16];
    *(bf16x8*)r0 = c00; *(bf16x8*)(r0 + 8) = c01;
    *(bf16x8*)r1 = c10; *(bf16x8*)(r1 + 8) = c11;
  }
  __threadfence_block();                  // wave-local LDS visibility

  // ---- A fragments: px = pt*16 + m, k-halves q*8 / 32+q*8 ------------------
  bf16x8 A00 = *(const bf16x8*)&Zl[(m) * 72 + q * 8];
  bf16x8 A01 = *(const bf16x8*)&Zl[(m) * 72 + 32 + q * 8];
  bf16x8 A10 = *(const bf16x8*)&Zl[(16 + m) * 72 + q * 8];
  bf16x8 A11 = *(const bf16x8*)&Zl[(16 + m) * 72 + 32 + q * 8];

  unsigned k00 = ~0u, k01 = ~0u, k02 = ~0u, k03 = ~0u;
  unsigned k10 = ~0u, k11 = ~0u, k12 = ~0u, k13 = ~0u;

  // ---- stream all 512 codes: 32 tiles, depth-4 prefetch ring ---------------
  const __bf16* Eb = E16s + lane * 8;     // + ct*1024 (+512 for B1)
  bf16x8 P0[4], P1[4];
  float  PE[4];
  #pragma unroll
  for (int i = 0; i < 4; ++i) {
    P0[i] = *(const bf16x8*)(Eb + i * 1024);
    P1[i] = *(const bf16x8*)(Eb + i * 1024 + 512);
    PE[i] = en2s[i * 64 + lane];
  }
  #pragma unroll
  for (int ct = 0; ct < 32; ++ct) {
    const int s = ct & 3;
    bf16x8 B0 = P0[s], B1 = P1[s];
    float  en = PE[s];
    {                                     // refill slot with tile (ct+4)&31
      int nt = (ct + 4) & 31;             // wrap: tiles 0..3 are L1-hot
      P0[s] = *(const bf16x8*)(Eb + nt * 1024);
      P1[s] = *(const bf16x8*)(Eb + nt * 1024 + 512);
      PE[s] = en2s[nt * 64 + lane];
    }
    f32x4 einit = {en, en, en, en};
    const unsigned cvec = (unsigned)(ct * 16 + m);
    f32x4 a0 = __builtin_amdgcn_mfma_f32_16x16x32_bf16(A00, B0, einit, 0, 0, 0);
    a0 = __builtin_amdgcn_mfma_f32_16x16x32_bf16(A01, B1, a0, 0, 0, 0);
    f32x4 a1 = __builtin_amdgcn_mfma_f32_16x16x32_bf16(A10, B0, einit, 0, 0, 0);
    a1 = __builtin_amdgcn_mfma_f32_16x16x32_bf16(A11, B1, a1, 0, 0, 0);
    ARGMIN(k00, a0[0]) ARGMIN(k01, a0[1]) ARGMIN(k02, a0[2]) ARGMIN(k03, a0[3])
    ARGMIN(k10, a1[0]) ARGMIN(k11, a1[1]) ARGMIN(k12, a1[2]) ARGMIN(k13, a1[3])
  }

  // ---- merge across the 16 code-column lanes -------------------------------
  MERGE16(k00) MERGE16(k01) MERGE16(k02) MERGE16(k03)
  MERGE16(k10) MERGE16(k11) MERGE16(k12) MERGE16(k13)

  if (m == 0) {                           // publish winners: px = pt*16+q*4+r
    i32x4 w0, w1;
    w0[0] = (int)(k00 & 511u); w0[1] = (int)(k01 & 511u);
    w0[2] = (int)(k02 & 511u); w0[3] = (int)(k03 & 511u);
    w1[0] = (int)(k10 & 511u); w1[1] = (int)(k11 & 511u);
    w1[2] = (int)(k12 & 511u); w1[3] = (int)(k13 & 511u);
    *(i32x4*)&idxl[w][q * 4]      = w0;
    *(i32x4*)&idxl[w][16 + q * 4] = w1;
  }

  // ---- loss partial --------------------------------------------------------
  float ll = zn;
  if (m == 0) {
    ll += (__uint_as_float(k00) - 2.f) + (__uint_as_float(k01) - 2.f)
        + (__uint_as_float(k02) - 2.f) + (__uint_as_float(k03) - 2.f)
        + (__uint_as_float(k10) - 2.f) + (__uint_as_float(k11) - 2.f)
        + (__uint_as_float(k12) - 2.f) + (__uint_as_float(k13) - 2.f);
  }
  #pragma unroll
  for (int off = 1; off < 64; off <<= 1) ll += __shfl_xor(ll, off);
  if (lane == 0) cells[g] = ll;

  __threadfence_block();                  // idxl visible within the wave

  // ---- cooperative gather: 16 lanes fetch one row; 4 rows/instr ------------
  // step j: px p = j*4 + q; lane fetches dims 4m..4m+3 -> zqT[d][p]
  float* zqT = &arena[w][0];              // [64][33], 8448 B — fits the arena
  #pragma unroll
  for (int j = 0; j < 8; ++j) {
    int p = j * 4 + q;
    int row = idxl[w][p];
    float4 v = *(const float4*)(E + row * 64 + m * 4);
    zqT[(4 * m + 0) * 33 + p] = v.x;
    zqT[(4 * m + 1) * 33 + p] = v.y;
    zqT[(4 * m + 2) * 33 + p] = v.z;
    zqT[(4 * m + 3) * 33 + p] = v.w;
  }
  __threadfence_block();

  // ---- store: lane (q,m) -> d = j*4+q, px 2m,2m+1 (dwordx2, nontemporal) ---
  {
    float* op = out + 1 + base + 2 * m;
    #pragma unroll
    for (int j = 0; j < 16; ++j) {
      int d = j * 4 + q;
      f32x2u v;
      v[0] = zqT[d * 33 + 2 * m];
      v[1] = zqT[d * 33 + 2 * m + 1];
      __builtin_nontemporal_store(v, (f32x2u*)(op + d * 4096));
    }
  }
}

// ---- tiny reduce: sum 4096 wave partials -> out[0] -------------------------
__global__ __launch_bounds__(256) void vq_loss(const float* __restrict__ cells,
                                               float* __restrict__ out) {
  __shared__ float wsum[4];
  int t = threadIdx.x;
  const float4* c4 = (const float4*)cells;         // 1024 float4
  float s = 0.f;
  #pragma unroll
  for (int j = 0; j < 4; ++j) {
    float4 v = c4[t + 256 * j];
    s += v.x + v.y + v.z + v.w;
  }
  #pragma unroll
  for (int off = 1; off < 64; off <<= 1) s += __shfl_xor(s, off);
  if ((t & 63) == 0) wsum[t >> 6] = s;
  __syncthreads();
  if (t == 0) out[0] = (wsum[0] + wsum[1] + wsum[2] + wsum[3]) * LOSS_SCALE;
}

extern "C" void kernel_launch(void* const* d_in, const int* in_sizes, int n_in,
                              void* d_out, int out_size, void* d_ws, size_t ws_size,
                              hipStream_t stream) {
  (void)in_sizes; (void)n_in; (void)out_size; (void)ws_size;
  const float* in = (const float*)d_in[0];   // [32,64,64,64]
  const float* E  = (const float*)d_in[1];   // [512,64]
  float* out = (float*)d_out;                // [1 + 8388608]
  __bf16* E16s  = (__bf16*)d_ws;                       // 64 KiB
  float*  en2s  = (float*)((char*)d_ws + 65536);       // 8 KiB
  float*  cells = (float*)((char*)d_ws + 73728);       // 16 KiB

  vq_prep<<<16, 256, 0, stream>>>(E, E16s, en2s);
  vq_main<<<1024, 256, 0, stream>>>(in, E, E16s, en2s, out, cells);
  vq_loss<<<1, 256, 0, stream>>>(cells, out);
}